// Round 20
// baseline (264.415 us; speedup 1.0000x reference)
//
#include <hip/hip_runtime.h>

#define B_   4
#define C_   512
#define S_   4096
#define G_   32
#define CPG_ 16
#define EPS_ 1e-6f

typedef unsigned short u16;
typedef __bf16 bf16x8 __attribute__((ext_vector_type(8)));
typedef float  f32x4  __attribute__((ext_vector_type(4)));

__device__ __forceinline__ u16 f2bf(float f) {
  unsigned u = __float_as_uint(f);
  u += 0x7fffu + ((u >> 16) & 1u);   // RNE
  return (u16)(u >> 16);
}
__device__ __forceinline__ float bf2f(u16 h) {
  return __uint_as_float((unsigned)h << 16);
}

__device__ __forceinline__ void g2lds16(const void* g, void* l) {
  __builtin_amdgcn_global_load_lds(
      (const __attribute__((address_space(1))) void*)g,
      (__attribute__((address_space(3))) void*)l, 16, 0, 0);
}

#define BAR()    __builtin_amdgcn_s_barrier()
#define SCHED0() __builtin_amdgcn_sched_barrier(0)
#define WAITV4   asm volatile("s_waitcnt vmcnt(4)" ::: "memory")
#define WAITV0   asm volatile("s_waitcnt vmcnt(0)" ::: "memory")

// chunked XCD swizzle (bijective when nwg % 8 == 0 — all grids here satisfy it)
__device__ __forceinline__ void xcd_swz(int& bx, int& by, int& bz) {
  const int gx = gridDim.x, gy = gridDim.y;
  const int nwg = gx * gy * (int)gridDim.z;
  const int flat = blockIdx.x + gx * (blockIdx.y + gy * blockIdx.z);
  const int q = nwg >> 3;
  const int nf = (flat & 7) * q + (flat >> 3);
  bx = nf % gx;
  const int r = nf / gx;
  by = r % gy;
  bz = r / gy;
}

// ---- fused prep: 4x fp32->bf16 weight conversion + bias concat, one dispatch ----
// wout = contiguous [wq|wk|wv|wo] bf16 region (4 x 262144).
__global__ __launch_bounds__(256) void prep(const float* __restrict__ wq,
                                            const float* __restrict__ wk,
                                            const float* __restrict__ wv,
                                            const float* __restrict__ wo,
                                            const float* __restrict__ bq,
                                            const float* __restrict__ bk,
                                            u16* __restrict__ wout,
                                            float* __restrict__ bqk) {
  const int bid = blockIdx.x;
  const int tid = threadIdx.x;
  if (bid < 4096) {
    const int i = bid * 256 + tid;          // 0..1048575
    const int sel = i >> 18;                // which weight matrix
    const int off = i & 262143;
    const float* src = (sel == 0) ? wq : (sel == 1) ? wk : (sel == 2) ? wv : wo;
    wout[i] = f2bf(src[off]);
  } else {
    const int i = (bid - 4096) * 256 + tid; // 0..1023
    bqk[i] = (i < 512) ? bq[i] : bk[i - 512];
  }
}

// ---------------- softmax denominator: Lr[b,i] = 1/sum_jb partial ----------------
__global__ __launch_bounds__(256) void reduce_l(const float* __restrict__ p,
                                                float* __restrict__ lr) {
  const int i = blockIdx.x * 256 + threadIdx.x;   // 16384 = B*S
  const int b = i >> 12, row = i & 4095;
  float s = 0.f;
#pragma unroll
  for (int jb = 0; jb < 16; ++jb) s += p[((size_t)(b * 16 + jb) << 12) + row];
  lr[i] = 1.f / s;
}

// ------- GroupNorm stats, BW-saturating (2048 blocks; finalize fused downstream) -------
__global__ __launch_bounds__(256) void gn_stats_part(const float* __restrict__ x,
                                                     float* __restrict__ part) {
  const int blk = blockIdx.x;               // 0..2047
  const float4* p4 = (const float4*)(x + (size_t)blk * 4096);
  float s = 0.f, ss = 0.f;
  const int tid = threadIdx.x;
#pragma unroll
  for (int i = 0; i < 4; ++i) {
    const float4 v = p4[tid + i * 256];
    s  += v.x + v.y + v.z + v.w;
    ss += v.x * v.x + v.y * v.y + v.z * v.z + v.w * v.w;
  }
#pragma unroll
  for (int o = 32; o; o >>= 1) { s += __shfl_xor(s, o, 64); ss += __shfl_xor(ss, o, 64); }
  __shared__ float sm[8];
  const int wid = tid >> 6, lane = tid & 63;
  if (lane == 0) { sm[wid * 2] = s; sm[wid * 2 + 1] = ss; }
  __syncthreads();
  if (tid == 0) {
    part[blk * 2]     = sm[0] + sm[2] + sm[4] + sm[6];
    part[blk * 2 + 1] = sm[1] + sm[3] + sm[5] + sm[7];
  }
}

// ---- normalize + transpose, vectorized, stats finalize fused in-block ----
// 64(c) x 64(s) tile per block, 2048 blocks. Threads 0-3 finalize the block's
// 4 group-stats from gnp partials (fixed-order, deterministic, L2-resident);
// then float4 reads -> LDS [64][65] fp32 staging -> short4 writes.
__global__ __launch_bounds__(256) void gn_apply_t(const float* __restrict__ x,
                                                  const float* __restrict__ gamma,
                                                  const float* __restrict__ beta,
                                                  const float* __restrict__ gnp,
                                                  u16* __restrict__ ht) {
  __shared__ float tile[64][65];
  __shared__ float gstat[4][2];
  const int b = blockIdx.z, c0 = blockIdx.y * 64, s0 = blockIdx.x * 64;
  const int tid = threadIdx.x;
  if (tid < 4) {
    const int g = b * G_ + (c0 >> 4) + tid;
    float s = 0.f, ss = 0.f;
#pragma unroll
    for (int i = 0; i < 16; ++i) {
      s  += gnp[(g * 16 + i) * 2];
      ss += gnp[(g * 16 + i) * 2 + 1];
    }
    const float inv = 1.f / (float)(CPG_ * S_);
    const float mu = s * inv;
    const float var = ss * inv - mu * mu;
    gstat[tid][0] = mu;
    gstat[tid][1] = rsqrtf(var + EPS_);
  }
  __syncthreads();
  const int tq = tid >> 4, tr = tid & 15;   // 16 groups x 16 lanes
#pragma unroll
  for (int i = 0; i < 4; ++i) {
    const int cl = i * 16 + tq;             // local c row
    const int c  = c0 + cl;
    const float mu = gstat[cl >> 4][0];
    const float rs = gstat[cl >> 4][1];
    const float ga = gamma[c], be = beta[c];
    const float4 v = *(const float4*)&x[((size_t)b * C_ + c) * S_ + s0 + tr * 4];
    tile[cl][tr * 4 + 0] = (v.x - mu) * rs * ga + be;
    tile[cl][tr * 4 + 1] = (v.y - mu) * rs * ga + be;
    tile[cl][tr * 4 + 2] = (v.z - mu) * rs * ga + be;
    tile[cl][tr * 4 + 3] = (v.w - mu) * rs * ga + be;
  }
  __syncthreads();
#pragma unroll
  for (int i = 0; i < 4; ++i) {
    const int sl = i * 16 + tq;             // local s row
    const int cl = tr * 4;                  // local c (4 consecutive)
    u16 o[4];
#pragma unroll
    for (int j = 0; j < 4; ++j) o[j] = f2bf(tile[cl + j][sl]);
    *(uint2*)&ht[((size_t)b * S_ + s0 + sl) * C_ + c0 + cl] = *(const uint2*)o;
  }
}

// ======= 256x256 8-phase GEMM — single barrier/phase, compiler-counted lgkm =======
// C[m,n] = alpha * sum_k A[m,k]*B[n,k] (+bias[n]); A,B bf16 K-contiguous.
// 512 thr = 8 waves (2M x 4N), strided frags: m-frag f at wm+f*32, n-frag g at
// wn+g*64. LDS As/Bs[2 dbuf][2 half][128][64] u16; swizzle phys granule = g^(row&7).
// Phase = {ds_reads; stage; [counted vmcnt]; BAR; setprio(1) MFMA setprio(0)}.
// NO hard lgkmcnt(0): compiler emits per-fragment counted lgkm waits so MFMA
// starts as soon as its first frags land, and next phase's reads/stages issue
// under the MFMA tail. Counted vmcnt(4) at p3/p7 pre-barrier (asm volatile,
// unhoistable) drains exactly the 8 loads of the dbuf read next; steady state
// 12 loads in flight, never 0.
// ZMODE 1 = PV split-K: bz -> (b = bz>>1, kh = bz&1), hardcoded offsets.
// SMAX 1 = scores epilogue: write exp(alpha*acc) bf16 + per-block row-sum partials.
template <int BIAS_MODE, int ZMODE, int SMAX>
__global__ __launch_bounds__(512, 2) void gemm8p(
    const u16* __restrict__ Ag, int lda, long sA,
    const u16* __restrict__ Bg, int ldb, long sB,
    u16* __restrict__ Cg, int ldc, long sC,
    const float* __restrict__ bias, float alpha, int K,
    float* __restrict__ smx) {
  __shared__ u16 As[2][2][8192];
  __shared__ u16 Bs[2][2][8192];
  __shared__ float ps[4][256];
  int bx, by, bz;
  xcd_swz(bx, by, bz);
  const u16 *A, *Bm;
  u16* Cb;
  if (ZMODE == 0) {
    A = Ag + (size_t)bz * sA; Bm = Bg + (size_t)bz * sB; Cb = Cg + (size_t)bz * sC;
  } else {  // PV split-K: A = P[b], cols kh*2048+; B = V rows, cols b*4096+kh*2048+
    const int b = bz >> 1, kh = bz & 1;
    A  = Ag + (size_t)b * 16777216 + (size_t)kh * 2048;
    Bm = Bg + (size_t)b * 4096 + (size_t)kh * 2048;
    Cb = Cg + (size_t)kh * 8388608 + (size_t)b * 2097152;
  }
  const int bm = by * 256, bn = bx * 256;
  const int tid = threadIdx.x;
  const int wid = tid >> 6, lane = tid & 63;
  const int wm = (wid >> 2) * 16, wn = (wid & 3) * 16;
  const int lr = lane & 15, lh = lane >> 4;
  const int x7 = lr & 7;
  const int g0 = (lh ^ x7) * 8, g1 = ((4 | lh) ^ x7) * 8;  // swizzled granule offs (kh=0/1)

  // staging: wave w covers rows w*8..w*8+7 (+64) of each half; pre-swizzled source
  const int sg = (lane & 7) ^ ((lane >> 3) & 7);
  const u16* Abase = A  + (size_t)(bm + wid * 8 + (lane >> 3)) * lda + sg * 8;
  const u16* Bbase = Bm + (size_t)(bn + wid * 8 + (lane >> 3)) * ldb + sg * 8;

#define STGA(D, H, T) do {                                                   \
    const u16* _s = Abase + (size_t)((H) * 128) * lda + (size_t)(T) * 64;    \
    g2lds16(_s,                    &As[D][H][wid * 512]);                    \
    g2lds16(_s + (size_t)64 * lda, &As[D][H][4096 + wid * 512]);             \
  } while (0)
#define STGB(D, H, T) do {                                                   \
    const u16* _s = Bbase + (size_t)((H) * 128) * ldb + (size_t)(T) * 64;    \
    g2lds16(_s,                    &Bs[D][H][wid * 512]);                    \
    g2lds16(_s + (size_t)64 * ldb, &Bs[D][H][4096 + wid * 512]);             \
  } while (0)

  // bias preload FIRST: its 4 loads are oldest, drained by the prologue vmcnt(4)
  float bias_v[4] = {0.f, 0.f, 0.f, 0.f};
  if (BIAS_MODE == 1) {
#pragma unroll
    for (int g = 0; g < 4; ++g) bias_v[g] = bias[bn + wn + g * 64 + lr];
  }
  SCHED0();

  f32x4 acc[8][4];
  const f32x4 zero = {0.f, 0.f, 0.f, 0.f};
#pragma unroll
  for (int i = 0; i < 8; ++i)
#pragma unroll
    for (int j = 0; j < 4; ++j) acc[i][j] = zero;

  bf16x8 a_[4][2], b_[4][2];

#define RDA(D, AH) do {                                                      \
    _Pragma("unroll") for (int i = 0; i < 4; ++i) {                          \
      const int _o = (wm + i * 32 + lr) * 64;                                \
      a_[i][0] = *(const bf16x8*)&As[D][AH][_o + g0];                        \
      a_[i][1] = *(const bf16x8*)&As[D][AH][_o + g1];                        \
    } } while (0)
#define RDB(D, BH) do {                                                      \
    _Pragma("unroll") for (int j = 0; j < 2; ++j) {                          \
      const int _o = (wn + j * 64 + lr) * 64;                                \
      b_[(BH) * 2 + j][0] = *(const bf16x8*)&Bs[D][BH][_o + g0];             \
      b_[(BH) * 2 + j][1] = *(const bf16x8*)&Bs[D][BH][_o + g1];             \
    } } while (0)
#define MM(AH, BH) do {                                                      \
    __builtin_amdgcn_s_setprio(1);                                           \
    _Pragma("unroll") for (int i = 0; i < 4; ++i)                            \
    _Pragma("unroll") for (int j = 0; j < 2; ++j) {                          \
      acc[(AH) * 4 + i][(BH) * 2 + j] = __builtin_amdgcn_mfma_f32_16x16x32_bf16( \
          a_[i][0], b_[(BH) * 2 + j][0], acc[(AH) * 4 + i][(BH) * 2 + j], 0, 0, 0); \
      acc[(AH) * 4 + i][(BH) * 2 + j] = __builtin_amdgcn_mfma_f32_16x16x32_bf16( \
          a_[i][1], b_[(BH) * 2 + j][1], acc[(AH) * 4 + i][(BH) * 2 + j], 0, 0, 0); \
    }                                                                        \
    __builtin_amdgcn_s_setprio(0);                                           \
  } while (0)

  // prologue: tile0 all 4 halves, then tile1 A0,B1; drain tile0 BEFORE the barrier
  STGA(0, 0, 0); STGB(0, 1, 0); STGA(0, 1, 0); STGB(0, 0, 0);
  STGA(1, 0, 1); STGB(1, 1, 1);
  WAITV4;
  BAR();

  const int nt = K >> 6;  // even, >= 4
  for (int i = 0; i < nt / 2; ++i) {
    const int t1 = 2 * i + 1, t2 = 2 * i + 2, t3 = 2 * i + 3;
    const bool s2 = t2 < nt, s3 = t3 < nt;
    // p0 (d0, A0,B0)
    RDA(0, 0); RDB(0, 0);
    STGB(1, 0, t1);
    BAR(); MM(0, 0);
    // p1 (d0, A0,B1)
    RDB(0, 1);
    STGA(1, 1, t1);
    BAR(); MM(0, 1);
    // p2 (d0, A1,B1)
    RDA(0, 1);
    if (s2) STGA(0, 0, t2);
    BAR(); MM(1, 1);
    // p3 (d0, A1,B0) — counted drain of d1's stages before the phase barrier
    if (s2) STGB(0, 1, t2);
    if (s2) { WAITV4; } else { WAITV0; }
    BAR(); MM(1, 0);
    // p4 (d1, A0,B0)
    RDA(1, 0); RDB(1, 0);
    if (s2) STGA(0, 1, t2);
    BAR(); MM(0, 0);
    // p5 (d1, A0,B1)
    RDB(1, 1);
    if (s2) STGB(0, 0, t2);
    BAR(); MM(0, 1);
    // p6 (d1, A1,B1)
    RDA(1, 1);
    if (s3) STGA(1, 0, t3);
    BAR(); MM(1, 1);
    // p7 (d1, A1,B0) — counted drain of next d0's stages before the phase barrier
    if (s3) STGB(1, 1, t3);
    if (s3) { WAITV4; }
    BAR(); MM(1, 0);
  }
#undef STGA
#undef STGB
#undef RDA
#undef RDB
#undef MM
  SCHED0();

  if (SMAX) {
    // P = exp(alpha*s) bf16 + per-(row, col-block) partial sums -> smx
    float rs[8][4];
#pragma unroll
    for (int f = 0; f < 8; ++f) {
      const int row0 = bm + wm + f * 32 + lh * 4;
#pragma unroll
      for (int r = 0; r < 4; ++r) rs[f][r] = 0.f;
#pragma unroll
      for (int g = 0; g < 4; ++g) {
        const int col = bn + wn + g * 64 + lr;
#pragma unroll
        for (int r = 0; r < 4; ++r) {
          const float e = __expf(acc[f][g][r] * alpha);
          rs[f][r] += e;
          Cb[(size_t)(row0 + r) * ldc + col] = f2bf(e);
        }
      }
#pragma unroll
      for (int r = 0; r < 4; ++r) {
        float v = rs[f][r];
        v += __shfl_xor(v, 1, 64);
        v += __shfl_xor(v, 2, 64);
        v += __shfl_xor(v, 4, 64);
        v += __shfl_xor(v, 8, 64);
        rs[f][r] = v;
      }
    }
    // cross-wave (over wn) reduction: compile-time-predicated LDS writes
#pragma unroll
    for (int f = 0; f < 8; ++f)
#pragma unroll
      for (int r = 0; r < 4; ++r)
        if (lr == ((f << 1) | (r >> 1)))
          ps[wid & 3][wm + f * 32 + lh * 4 + r] = rs[f][r];
    __syncthreads();
    if (tid < 256) {
      const float tot = ps[0][tid] + ps[1][tid] + ps[2][tid] + ps[3][tid];
      smx[((size_t)(bz * 16 + bx) << 12) + bm + tid] = tot;
    }
  } else {
#pragma unroll
    for (int f = 0; f < 8; ++f) {
      const int row0 = bm + wm + f * 32 + lh * 4;
#pragma unroll
      for (int g = 0; g < 4; ++g) {
        const int col = bn + wn + g * 64 + lr;
#pragma unroll
        for (int r = 0; r < 4; ++r)
          Cb[(size_t)(row0 + r) * ldc + col] = f2bf(acc[f][g][r] * alpha + bias_v[g]);
      }
    }
  }
}

// ---------------- 128x128 GEMM (V-proj and out-proj) ----------------
// BCOMB=1: B-operand is the fp32 sum of two bf16 psum buffers (Bg, Bg2), added
// during reg-staged B-staging (replaces the separate add_scale pass).
// OUT_MODE=1: fp32 out[b,o,s] = acc*lscale[n] + bias[m] + xres, n = b*S+s.
#define GBM 128
#define GBN 128
#define GBK 64

template <int BIAS_MODE, int OUT_MODE, int BCOMB>
__global__ __launch_bounds__(256) void gemm_abT(
    const u16* __restrict__ Ag, int lda, long sA,
    const u16* __restrict__ Bg, int ldb, long sB,
    void* __restrict__ Cg, int ldc, long sC,
    const float* __restrict__ bias, float alpha,
    const float* __restrict__ xres, const float* __restrict__ lscale,
    const u16* __restrict__ Bg2, int K) {
  __shared__ u16 As[GBM * GBK];
  __shared__ u16 Bs[GBN * GBK];
  const int bz = blockIdx.z;
  const u16* A    = Ag + (size_t)bz * sA;
  const u16* Bmat = Bg + (size_t)bz * sB;
  const int bm = blockIdx.y * GBM, bn = blockIdx.x * GBN;
  const int tid = threadIdx.x;
  const int wid = tid >> 6, lane = tid & 63;
  const int wm = (wid >> 1) * 64, wn = (wid & 1) * 64;
  const int lr = lane & 15, lh = lane >> 4;
  const int srow = lane >> 3, scol = (lane & 7) * 8;

  f32x4 acc[4][4];
  const f32x4 zero = {0.f, 0.f, 0.f, 0.f};
#pragma unroll
  for (int i = 0; i < 4; ++i)
#pragma unroll
    for (int j = 0; j < 4; ++j) acc[i][j] = zero;

  for (int k0 = 0; k0 < K; k0 += GBK) {
    __syncthreads();
#pragma unroll
    for (int i = 0; i < 4; ++i) {
      const int chunk = wid * 4 + i;
      const int row   = chunk * 8 + srow;
      g2lds16(A + (size_t)(bm + row) * lda + (k0 + scol), &As[chunk * 512]);
      if (BCOMB == 0) {
        g2lds16(Bmat + (size_t)(bn + row) * ldb + (k0 + scol), &Bs[chunk * 512]);
      } else {
        const size_t boff = (size_t)(bn + row) * ldb + (k0 + scol);
        const uint4 u0 = *(const uint4*)(Bmat + boff);
        const uint4 u1 = *(const uint4*)(Bg2 + boff);
        const unsigned* p0 = (const unsigned*)&u0;
        const unsigned* p1 = (const unsigned*)&u1;
        unsigned rr[4];
#pragma unroll
        for (int k = 0; k < 4; ++k) {
          const float lo = bf2f((u16)(p0[k] & 0xffffu)) + bf2f((u16)(p1[k] & 0xffffu));
          const float hi = bf2f((u16)(p0[k] >> 16)) + bf2f((u16)(p1[k] >> 16));
          rr[k] = (unsigned)f2bf(lo) | ((unsigned)f2bf(hi) << 16);
        }
        *(uint4*)&Bs[chunk * 512 + lane * 8] = *(const uint4*)rr;
      }
    }
    __syncthreads();
#pragma unroll
    for (int ks = 0; ks < 2; ++ks) {
      bf16x8 a_[4], b_[4];
#pragma unroll
      for (int m = 0; m < 4; ++m)
        a_[m] = *(const bf16x8*)&As[(wm + m * 16 + lr) * GBK + ks * 32 + lh * 8];
#pragma unroll
      for (int n = 0; n < 4; ++n)
        b_[n] = *(const bf16x8*)&Bs[(wn + n * 16 + lr) * GBK + ks * 32 + lh * 8];
#pragma unroll
      for (int m = 0; m < 4; ++m)
#pragma unroll
        for (int n = 0; n < 4; ++n)
          acc[m][n] = __builtin_amdgcn_mfma_f32_16x16x32_bf16(a_[m], b_[n], acc[m][n], 0, 0, 0);
    }
  }

  if (OUT_MODE == 0) {
    u16* Cb = (u16*)Cg + (size_t)bz * sC;
#pragma unroll
    for (int m = 0; m < 4; ++m) {
      const int row0 = bm + wm + m * 16 + lh * 4;
#pragma unroll
      for (int n = 0; n < 4; ++n) {
        const int col = bn + wn + n * 16 + lr;
        float bn_ = (BIAS_MODE == 1) ? bias[col] : 0.f;
#pragma unroll
        for (int r = 0; r < 4; ++r) {
          float bb = (BIAS_MODE == 2) ? bias[row0 + r] : bn_;
          Cb[(size_t)(row0 + r) * ldc + col] = f2bf(acc[m][n][r] * alpha + bb);
        }
      }
    }
  } else {
    float* Ob = (float*)Cg;
#pragma unroll
    for (int m = 0; m < 4; ++m) {
      const int row0 = bm + wm + m * 16 + lh * 4;
#pragma unroll
      for (int n = 0; n < 4; ++n) {
        const int col = bn + wn + n * 16 + lr;
        const int bb = col >> 12, sp = col & (S_ - 1);
        const float lsc = lscale[col];
#pragma unroll
        for (int r = 0; r < 4; ++r) {
          const int o = row0 + r;
          const size_t idx = ((size_t)bb * C_ + o) * S_ + sp;
          Ob[idx] = acc[m][n][r] * lsc + bias[o] + xres[idx];
        }
      }
    }
  }
}

extern "C" void kernel_launch(void* const* d_in, const int* in_sizes, int n_in,
                              void* d_out, int out_size, void* d_ws, size_t ws_size,
                              hipStream_t stream) {
  const float* x     = (const float*)d_in[0];
  const float* gamma = (const float*)d_in[1];
  const float* beta  = (const float*)d_in[2];
  const float* wq = (const float*)d_in[3];
  const float* bq = (const float*)d_in[4];
  const float* wk = (const float*)d_in[5];
  const float* bk = (const float*)d_in[6];
  const float* wv = (const float*)d_in[7];
  const float* bv = (const float*)d_in[8];
  const float* wo = (const float*)d_in[9];
  const float* bo = (const float*)d_in[10];
  float* out = (float*)d_out;

  // ws: pad 1KB | weights bf16 4x512KB | bqk 4KB | ht 16MB | qkt 32MB | vv 16MB
  //     | sc 128MB | partials 1MB | Lr 64KB | gn part 16KB
  char* ws = (char*)d_ws;
  u16* wqb = (u16*)(ws + 1024);
  u16* wkb = wqb + 262144;   // contiguous after wqb -> [wq;wk] is one 1024x512 matrix
  u16* wvb = wkb + 262144;
  u16* wob = wvb + 262144;
  float* bqk = (float*)(wob + 262144);
  u16* ht  = (u16*)((char*)bqk + 4096);  // [B*S, C]
  u16* qkt = ht + 8388608;               // [B*S, 1024] (q|k); later PV psum halves
  u16* vv  = qkt + 16777216;             // [C, B*S]
  u16* sc  = vv + 8388608;               // [B, S, S] exp(scores)
  float* partials = (float*)(sc + 67108864);  // [B][16][4096]
  float* Lr = partials + 262144;              // [B][4096]
  float* gnp = Lr + 16384;                    // [2048][2] gn stats partials

  // fused weight-convert + bias-concat (replaces 5 tiny dispatches)
  prep<<<4100, 256, 0, stream>>>(wq, wk, wv, wo, bq, bk, wqb, bqk);

  gn_stats_part<<<2048, 256, 0, stream>>>(x, gnp);
  gn_apply_t<<<dim3(64, 8, 4), 256, 0, stream>>>(x, gamma, beta, gnp, ht);

  // fused Q|K projection: qkt[bs, 0:512]=Q, [512:1024]=K   (256 blocks)
  gemm8p<1, 0, 0><<<dim3(4, 64, 1), 512, 0, stream>>>(ht, 512, 0, wqb, 512, 0,
                                                      qkt, 1024, 0, bqk, 1.f, 512, nullptr);
  // V[c, b*S+s]: bias per m (=c)                            (512 blocks)
  gemm_abT<2, 0, 0><<<dim3(128, 4, 1), 256, 0, stream>>>(wvb, 512, 0, ht, 512, 0,
                                                         vv, 16384, 0, bv, 1.f,
                                                         nullptr, nullptr, nullptr, 512);
  // P[b,i,j] = exp(scale * Q.K) + row-sum partials          (1024 blocks)
  gemm8p<0, 0, 1><<<dim3(16, 16, 4), 512, 0, stream>>>(qkt, 1024, 4194304, qkt + 512, 1024, 4194304,
                                                       sc, 4096, 16777216, nullptr,
                                                       0.04419417382415922f, 512, partials);
  reduce_l<<<64, 256, 0, stream>>>(partials, Lr);
  // PV split-K=2 on unnormalized P: psums in qkt halves     (256 blocks)
  gemm8p<0, 1, 0><<<dim3(2, 16, 8), 512, 0, stream>>>(sc, 4096, 0, vv, 16384, 0,
                                                      qkt, 512, 0, nullptr, 1.f, 2048, nullptr);
  // out[b,o,s] = (Wo @ (psum0+psum1)) * Lr[bs] + bo + x      (512 blocks)
  gemm_abT<2, 1, 1><<<dim3(128, 4, 1), 256, 0, stream>>>(wob, 512, 0, qkt, 512, 0,
                                                         out, 0, 0, bo, 1.f,
                                                         x, Lr, qkt + 8388608, 512);
}

// Round 21
// 263.933 us; speedup vs baseline: 1.0018x; 1.0018x over previous
//
#include <hip/hip_runtime.h>

#define B_   4
#define C_   512
#define S_   4096
#define G_   32
#define CPG_ 16
#define EPS_ 1e-6f

typedef unsigned short u16;
typedef __bf16 bf16x8 __attribute__((ext_vector_type(8)));
typedef float  f32x4  __attribute__((ext_vector_type(4)));

__device__ __forceinline__ u16 f2bf(float f) {
  unsigned u = __float_as_uint(f);
  u += 0x7fffu + ((u >> 16) & 1u);   // RNE
  return (u16)(u >> 16);
}
__device__ __forceinline__ float bf2f(u16 h) {
  return __uint_as_float((unsigned)h << 16);
}

__device__ __forceinline__ void g2lds16(const void* g, void* l) {
  __builtin_amdgcn_global_load_lds(
      (const __attribute__((address_space(1))) void*)g,
      (__attribute__((address_space(3))) void*)l, 16, 0, 0);
}

#define BAR()    __builtin_amdgcn_s_barrier()
#define SCHED0() __builtin_amdgcn_sched_barrier(0)
#define WAITV4   asm volatile("s_waitcnt vmcnt(4)" ::: "memory")
#define WAITV0   asm volatile("s_waitcnt vmcnt(0)" ::: "memory")

// chunked XCD swizzle (bijective when nwg % 8 == 0 — all grids here satisfy it)
__device__ __forceinline__ void xcd_swz(int& bx, int& by, int& bz) {
  const int gx = gridDim.x, gy = gridDim.y;
  const int nwg = gx * gy * (int)gridDim.z;
  const int flat = blockIdx.x + gx * (blockIdx.y + gy * blockIdx.z);
  const int q = nwg >> 3;
  const int nf = (flat & 7) * q + (flat >> 3);
  bx = nf % gx;
  const int r = nf / gx;
  by = r % gy;
  bz = r / gy;
}

// ---- fused prep: 4x fp32->bf16 weight conversion + bias concat, one dispatch ----
// wout = contiguous [wq|wk|wv|wo] bf16 region (4 x 262144).
__global__ __launch_bounds__(256) void prep(const float* __restrict__ wq,
                                            const float* __restrict__ wk,
                                            const float* __restrict__ wv,
                                            const float* __restrict__ wo,
                                            const float* __restrict__ bq,
                                            const float* __restrict__ bk,
                                            u16* __restrict__ wout,
                                            float* __restrict__ bqk) {
  const int bid = blockIdx.x;
  const int tid = threadIdx.x;
  if (bid < 4096) {
    const int i = bid * 256 + tid;          // 0..1048575
    const int sel = i >> 18;                // which weight matrix
    const int off = i & 262143;
    const float* src = (sel == 0) ? wq : (sel == 1) ? wk : (sel == 2) ? wv : wo;
    wout[i] = f2bf(src[off]);
  } else {
    const int i = (bid - 4096) * 256 + tid; // 0..1023
    bqk[i] = (i < 512) ? bq[i] : bk[i - 512];
  }
}

// ---------------- softmax denominator: Lr[b,i] = 1/sum_jb partial ----------------
__global__ __launch_bounds__(256) void reduce_l(const float* __restrict__ p,
                                                float* __restrict__ lr) {
  const int i = blockIdx.x * 256 + threadIdx.x;   // 16384 = B*S
  const int b = i >> 12, row = i & 4095;
  float s = 0.f;
#pragma unroll
  for (int jb = 0; jb < 16; ++jb) s += p[((size_t)(b * 16 + jb) << 12) + row];
  lr[i] = 1.f / s;
}

// ------- GroupNorm stats, BW-saturating 2-stage (2048 blocks -> 1 block) -------
__global__ __launch_bounds__(256) void gn_stats_part(const float* __restrict__ x,
                                                     float* __restrict__ part) {
  const int blk = blockIdx.x;               // 0..2047
  const float4* p4 = (const float4*)(x + (size_t)blk * 4096);
  float s = 0.f, ss = 0.f;
  const int tid = threadIdx.x;
#pragma unroll
  for (int i = 0; i < 4; ++i) {
    const float4 v = p4[tid + i * 256];
    s  += v.x + v.y + v.z + v.w;
    ss += v.x * v.x + v.y * v.y + v.z * v.z + v.w * v.w;
  }
#pragma unroll
  for (int o = 32; o; o >>= 1) { s += __shfl_xor(s, o, 64); ss += __shfl_xor(ss, o, 64); }
  __shared__ float sm[8];
  const int wid = tid >> 6, lane = tid & 63;
  if (lane == 0) { sm[wid * 2] = s; sm[wid * 2 + 1] = ss; }
  __syncthreads();
  if (tid == 0) {
    part[blk * 2]     = sm[0] + sm[2] + sm[4] + sm[6];
    part[blk * 2 + 1] = sm[1] + sm[3] + sm[5] + sm[7];
  }
}

// stage 2: one block, thread g finalizes group g from its 16 partials (deterministic)
__global__ __launch_bounds__(128) void gn_stats_fin(const float* __restrict__ part,
                                                    float* __restrict__ stats) {
  const int g = threadIdx.x;  // 0..127 = b*G_+grp
  float s = 0.f, ss = 0.f;
#pragma unroll
  for (int i = 0; i < 16; ++i) {
    s  += part[(g * 16 + i) * 2];
    ss += part[(g * 16 + i) * 2 + 1];
  }
  const float inv = 1.f / (float)(CPG_ * S_);
  const float mu = s * inv;
  const float var = ss * inv - mu * mu;
  stats[g * 2]     = mu;
  stats[g * 2 + 1] = rsqrtf(var + EPS_);
}

// ---- normalize + transpose, vectorized: x[b,c,s] -> ht[b*s, c] bf16 ----
// 64(c) x 64(s) tile per block, 2048 blocks. float4 reads (16B/lane), LDS
// [64][65] fp32 staging (both phases ~2-way banks = free), short4 writes
// (8B/lane, 128B per 16-lane segment). Math identical to the scalar version.
__global__ __launch_bounds__(256) void gn_apply_t(const float* __restrict__ x,
                                                  const float* __restrict__ gamma,
                                                  const float* __restrict__ beta,
                                                  const float* __restrict__ stats,
                                                  u16* __restrict__ ht) {
  __shared__ float tile[64][65];
  const int b = blockIdx.z, c0 = blockIdx.y * 64, s0 = blockIdx.x * 64;
  const int tid = threadIdx.x;
  const int tq = tid >> 4, tr = tid & 15;   // 16 groups x 16 lanes
#pragma unroll
  for (int i = 0; i < 4; ++i) {
    const int cl = i * 16 + tq;             // local c row
    const int c  = c0 + cl;
    const float mu = stats[(b * G_ + (c >> 4)) * 2];
    const float rs = stats[(b * G_ + (c >> 4)) * 2 + 1];
    const float ga = gamma[c], be = beta[c];
    const float4 v = *(const float4*)&x[((size_t)b * C_ + c) * S_ + s0 + tr * 4];
    tile[cl][tr * 4 + 0] = (v.x - mu) * rs * ga + be;
    tile[cl][tr * 4 + 1] = (v.y - mu) * rs * ga + be;
    tile[cl][tr * 4 + 2] = (v.z - mu) * rs * ga + be;
    tile[cl][tr * 4 + 3] = (v.w - mu) * rs * ga + be;
  }
  __syncthreads();
#pragma unroll
  for (int i = 0; i < 4; ++i) {
    const int sl = i * 16 + tq;             // local s row
    const int cl = tr * 4;                  // local c (4 consecutive)
    u16 o[4];
#pragma unroll
    for (int j = 0; j < 4; ++j) o[j] = f2bf(tile[cl + j][sl]);
    *(uint2*)&ht[((size_t)b * S_ + s0 + sl) * C_ + c0 + cl] = *(const uint2*)o;
  }
}

// ======= 256x256 8-phase GEMM — single barrier/phase, compiler-counted lgkm =======
// C[m,n] = alpha * sum_k A[m,k]*B[n,k] (+bias[n]); A,B bf16 K-contiguous.
// 512 thr = 8 waves (2M x 4N), strided frags: m-frag f at wm+f*32, n-frag g at
// wn+g*64. LDS As/Bs[2 dbuf][2 half][128][64] u16; swizzle phys granule = g^(row&7).
// Phase = {ds_reads; stage; [counted vmcnt]; BAR; setprio(1) MFMA setprio(0)}.
// NO hard lgkmcnt(0): compiler emits per-fragment counted lgkm waits so MFMA
// starts as soon as its first frags land, and next phase's reads/stages issue
// under the MFMA tail. Counted vmcnt(4) at p3/p7 pre-barrier (asm volatile,
// unhoistable) drains exactly the 8 loads of the dbuf read next; steady state
// 12 loads in flight, never 0.
// ZMODE 1 = PV split-K: bz -> (b = bz>>1, kh = bz&1), hardcoded offsets.
// SMAX 1 = scores epilogue: write exp(alpha*acc) bf16 + per-block row-sum partials.
template <int BIAS_MODE, int ZMODE, int SMAX>
__global__ __launch_bounds__(512, 2) void gemm8p(
    const u16* __restrict__ Ag, int lda, long sA,
    const u16* __restrict__ Bg, int ldb, long sB,
    u16* __restrict__ Cg, int ldc, long sC,
    const float* __restrict__ bias, float alpha, int K,
    float* __restrict__ smx) {
  __shared__ u16 As[2][2][8192];
  __shared__ u16 Bs[2][2][8192];
  __shared__ float ps[4][256];
  int bx, by, bz;
  xcd_swz(bx, by, bz);
  const u16 *A, *Bm;
  u16* Cb;
  if (ZMODE == 0) {
    A = Ag + (size_t)bz * sA; Bm = Bg + (size_t)bz * sB; Cb = Cg + (size_t)bz * sC;
  } else {  // PV split-K: A = P[b], cols kh*2048+; B = V rows, cols b*4096+kh*2048+
    const int b = bz >> 1, kh = bz & 1;
    A  = Ag + (size_t)b * 16777216 + (size_t)kh * 2048;
    Bm = Bg + (size_t)b * 4096 + (size_t)kh * 2048;
    Cb = Cg + (size_t)kh * 8388608 + (size_t)b * 2097152;
  }
  const int bm = by * 256, bn = bx * 256;
  const int tid = threadIdx.x;
  const int wid = tid >> 6, lane = tid & 63;
  const int wm = (wid >> 2) * 16, wn = (wid & 3) * 16;
  const int lr = lane & 15, lh = lane >> 4;
  const int x7 = lr & 7;
  const int g0 = (lh ^ x7) * 8, g1 = ((4 | lh) ^ x7) * 8;  // swizzled granule offs (kh=0/1)

  // staging: wave w covers rows w*8..w*8+7 (+64) of each half; pre-swizzled source
  const int sg = (lane & 7) ^ ((lane >> 3) & 7);
  const u16* Abase = A  + (size_t)(bm + wid * 8 + (lane >> 3)) * lda + sg * 8;
  const u16* Bbase = Bm + (size_t)(bn + wid * 8 + (lane >> 3)) * ldb + sg * 8;

#define STGA(D, H, T) do {                                                   \
    const u16* _s = Abase + (size_t)((H) * 128) * lda + (size_t)(T) * 64;    \
    g2lds16(_s,                    &As[D][H][wid * 512]);                    \
    g2lds16(_s + (size_t)64 * lda, &As[D][H][4096 + wid * 512]);             \
  } while (0)
#define STGB(D, H, T) do {                                                   \
    const u16* _s = Bbase + (size_t)((H) * 128) * ldb + (size_t)(T) * 64;    \
    g2lds16(_s,                    &Bs[D][H][wid * 512]);                    \
    g2lds16(_s + (size_t)64 * ldb, &Bs[D][H][4096 + wid * 512]);             \
  } while (0)

  // bias preload FIRST: its 4 loads are oldest, drained by the prologue vmcnt(4)
  float bias_v[4] = {0.f, 0.f, 0.f, 0.f};
  if (BIAS_MODE == 1) {
#pragma unroll
    for (int g = 0; g < 4; ++g) bias_v[g] = bias[bn + wn + g * 64 + lr];
  }
  SCHED0();

  f32x4 acc[8][4];
  const f32x4 zero = {0.f, 0.f, 0.f, 0.f};
#pragma unroll
  for (int i = 0; i < 8; ++i)
#pragma unroll
    for (int j = 0; j < 4; ++j) acc[i][j] = zero;

  bf16x8 a_[4][2], b_[4][2];

#define RDA(D, AH) do {                                                      \
    _Pragma("unroll") for (int i = 0; i < 4; ++i) {                          \
      const int _o = (wm + i * 32 + lr) * 64;                                \
      a_[i][0] = *(const bf16x8*)&As[D][AH][_o + g0];                        \
      a_[i][1] = *(const bf16x8*)&As[D][AH][_o + g1];                        \
    } } while (0)
#define RDB(D, BH) do {                                                      \
    _Pragma("unroll") for (int j = 0; j < 2; ++j) {                          \
      const int _o = (wn + j * 64 + lr) * 64;                                \
      b_[(BH) * 2 + j][0] = *(const bf16x8*)&Bs[D][BH][_o + g0];             \
      b_[(BH) * 2 + j][1] = *(const bf16x8*)&Bs[D][BH][_o + g1];             \
    } } while (0)
#define MM(AH, BH) do {                                                      \
    __builtin_amdgcn_s_setprio(1);                                           \
    _Pragma("unroll") for (int i = 0; i < 4; ++i)                            \
    _Pragma("unroll") for (int j = 0; j < 2; ++j) {                          \
      acc[(AH) * 4 + i][(BH) * 2 + j] = __builtin_amdgcn_mfma_f32_16x16x32_bf16( \
          a_[i][0], b_[(BH) * 2 + j][0], acc[(AH) * 4 + i][(BH) * 2 + j], 0, 0, 0); \
      acc[(AH) * 4 + i][(BH) * 2 + j] = __builtin_amdgcn_mfma_f32_16x16x32_bf16( \
          a_[i][1], b_[(BH) * 2 + j][1], acc[(AH) * 4 + i][(BH) * 2 + j], 0, 0, 0); \
    }                                                                        \
    __builtin_amdgcn_s_setprio(0);                                           \
  } while (0)

  // prologue: tile0 all 4 halves, then tile1 A0,B1; drain tile0 BEFORE the barrier
  STGA(0, 0, 0); STGB(0, 1, 0); STGA(0, 1, 0); STGB(0, 0, 0);
  STGA(1, 0, 1); STGB(1, 1, 1);
  WAITV4;
  BAR();

  const int nt = K >> 6;  // even, >= 4
  for (int i = 0; i < nt / 2; ++i) {
    const int t1 = 2 * i + 1, t2 = 2 * i + 2, t3 = 2 * i + 3;
    const bool s2 = t2 < nt, s3 = t3 < nt;
    // p0 (d0, A0,B0)
    RDA(0, 0); RDB(0, 0);
    STGB(1, 0, t1);
    BAR(); MM(0, 0);
    // p1 (d0, A0,B1)
    RDB(0, 1);
    STGA(1, 1, t1);
    BAR(); MM(0, 1);
    // p2 (d0, A1,B1)
    RDA(0, 1);
    if (s2) STGA(0, 0, t2);
    BAR(); MM(1, 1);
    // p3 (d0, A1,B0) — counted drain of d1's stages before the phase barrier
    if (s2) STGB(0, 1, t2);
    if (s2) { WAITV4; } else { WAITV0; }
    BAR(); MM(1, 0);
    // p4 (d1, A0,B0)
    RDA(1, 0); RDB(1, 0);
    if (s2) STGA(0, 1, t2);
    BAR(); MM(0, 0);
    // p5 (d1, A0,B1)
    RDB(1, 1);
    if (s2) STGB(0, 0, t2);
    BAR(); MM(0, 1);
    // p6 (d1, A1,B1)
    RDA(1, 1);
    if (s3) STGA(1, 0, t3);
    BAR(); MM(1, 1);
    // p7 (d1, A1,B0) — counted drain of next d0's stages before the phase barrier
    if (s3) STGB(1, 1, t3);
    if (s3) { WAITV4; }
    BAR(); MM(1, 0);
  }
#undef STGA
#undef STGB
#undef RDA
#undef RDB
#undef MM
  SCHED0();

  if (SMAX) {
    // P = exp(alpha*s) bf16 + per-(row, col-block) partial sums -> smx
    float rs[8][4];
#pragma unroll
    for (int f = 0; f < 8; ++f) {
      const int row0 = bm + wm + f * 32 + lh * 4;
#pragma unroll
      for (int r = 0; r < 4; ++r) rs[f][r] = 0.f;
#pragma unroll
      for (int g = 0; g < 4; ++g) {
        const int col = bn + wn + g * 64 + lr;
#pragma unroll
        for (int r = 0; r < 4; ++r) {
          const float e = __expf(acc[f][g][r] * alpha);
          rs[f][r] += e;
          Cb[(size_t)(row0 + r) * ldc + col] = f2bf(e);
        }
      }
#pragma unroll
      for (int r = 0; r < 4; ++r) {
        float v = rs[f][r];
        v += __shfl_xor(v, 1, 64);
        v += __shfl_xor(v, 2, 64);
        v += __shfl_xor(v, 4, 64);
        v += __shfl_xor(v, 8, 64);
        rs[f][r] = v;
      }
    }
    // cross-wave (over wn) reduction: compile-time-predicated LDS writes
#pragma unroll
    for (int f = 0; f < 8; ++f)
#pragma unroll
      for (int r = 0; r < 4; ++r)
        if (lr == ((f << 1) | (r >> 1)))
          ps[wid & 3][wm + f * 32 + lh * 4 + r] = rs[f][r];
    __syncthreads();
    if (tid < 256) {
      const float tot = ps[0][tid] + ps[1][tid] + ps[2][tid] + ps[3][tid];
      smx[((size_t)(bz * 16 + bx) << 12) + bm + tid] = tot;
    }
  } else {
#pragma unroll
    for (int f = 0; f < 8; ++f) {
      const int row0 = bm + wm + f * 32 + lh * 4;
#pragma unroll
      for (int g = 0; g < 4; ++g) {
        const int col = bn + wn + g * 64 + lr;
#pragma unroll
        for (int r = 0; r < 4; ++r)
          Cb[(size_t)(row0 + r) * ldc + col] = f2bf(acc[f][g][r] * alpha + bias_v[g]);
      }
    }
  }
}

// ---------------- 128x128 GEMM (V-proj and out-proj) ----------------
// BCOMB=1: B-operand is the fp32 sum of two bf16 psum buffers (Bg, Bg2), added
// during reg-staged B-staging (replaces the separate add_scale pass).
// OUT_MODE=1: fp32 out[b,o,s] = acc*lscale[n] + bias[m] + xres, n = b*S+s.
#define GBM 128
#define GBN 128
#define GBK 64

template <int BIAS_MODE, int OUT_MODE, int BCOMB>
__global__ __launch_bounds__(256) void gemm_abT(
    const u16* __restrict__ Ag, int lda, long sA,
    const u16* __restrict__ Bg, int ldb, long sB,
    void* __restrict__ Cg, int ldc, long sC,
    const float* __restrict__ bias, float alpha,
    const float* __restrict__ xres, const float* __restrict__ lscale,
    const u16* __restrict__ Bg2, int K) {
  __shared__ u16 As[GBM * GBK];
  __shared__ u16 Bs[GBN * GBK];
  const int bz = blockIdx.z;
  const u16* A    = Ag + (size_t)bz * sA;
  const u16* Bmat = Bg + (size_t)bz * sB;
  const int bm = blockIdx.y * GBM, bn = blockIdx.x * GBN;
  const int tid = threadIdx.x;
  const int wid = tid >> 6, lane = tid & 63;
  const int wm = (wid >> 1) * 64, wn = (wid & 1) * 64;
  const int lr = lane & 15, lh = lane >> 4;
  const int srow = lane >> 3, scol = (lane & 7) * 8;

  f32x4 acc[4][4];
  const f32x4 zero = {0.f, 0.f, 0.f, 0.f};
#pragma unroll
  for (int i = 0; i < 4; ++i)
#pragma unroll
    for (int j = 0; j < 4; ++j) acc[i][j] = zero;

  for (int k0 = 0; k0 < K; k0 += GBK) {
    __syncthreads();
#pragma unroll
    for (int i = 0; i < 4; ++i) {
      const int chunk = wid * 4 + i;
      const int row   = chunk * 8 + srow;
      g2lds16(A + (size_t)(bm + row) * lda + (k0 + scol), &As[chunk * 512]);
      if (BCOMB == 0) {
        g2lds16(Bmat + (size_t)(bn + row) * ldb + (k0 + scol), &Bs[chunk * 512]);
      } else {
        const size_t boff = (size_t)(bn + row) * ldb + (k0 + scol);
        const uint4 u0 = *(const uint4*)(Bmat + boff);
        const uint4 u1 = *(const uint4*)(Bg2 + boff);
        const unsigned* p0 = (const unsigned*)&u0;
        const unsigned* p1 = (const unsigned*)&u1;
        unsigned rr[4];
#pragma unroll
        for (int k = 0; k < 4; ++k) {
          const float lo = bf2f((u16)(p0[k] & 0xffffu)) + bf2f((u16)(p1[k] & 0xffffu));
          const float hi = bf2f((u16)(p0[k] >> 16)) + bf2f((u16)(p1[k] >> 16));
          rr[k] = (unsigned)f2bf(lo) | ((unsigned)f2bf(hi) << 16);
        }
        *(uint4*)&Bs[chunk * 512 + lane * 8] = *(const uint4*)rr;
      }
    }
    __syncthreads();
#pragma unroll
    for (int ks = 0; ks < 2; ++ks) {
      bf16x8 a_[4], b_[4];
#pragma unroll
      for (int m = 0; m < 4; ++m)
        a_[m] = *(const bf16x8*)&As[(wm + m * 16 + lr) * GBK + ks * 32 + lh * 8];
#pragma unroll
      for (int n = 0; n < 4; ++n)
        b_[n] = *(const bf16x8*)&Bs[(wn + n * 16 + lr) * GBK + ks * 32 + lh * 8];
#pragma unroll
      for (int m = 0; m < 4; ++m)
#pragma unroll
        for (int n = 0; n < 4; ++n)
          acc[m][n] = __builtin_amdgcn_mfma_f32_16x16x32_bf16(a_[m], b_[n], acc[m][n], 0, 0, 0);
    }
  }

  if (OUT_MODE == 0) {
    u16* Cb = (u16*)Cg + (size_t)bz * sC;
#pragma unroll
    for (int m = 0; m < 4; ++m) {
      const int row0 = bm + wm + m * 16 + lh * 4;
#pragma unroll
      for (int n = 0; n < 4; ++n) {
        const int col = bn + wn + n * 16 + lr;
        float bn_ = (BIAS_MODE == 1) ? bias[col] : 0.f;
#pragma unroll
        for (int r = 0; r < 4; ++r) {
          float bb = (BIAS_MODE == 2) ? bias[row0 + r] : bn_;
          Cb[(size_t)(row0 + r) * ldc + col] = f2bf(acc[m][n][r] * alpha + bb);
        }
      }
    }
  } else {
    float* Ob = (float*)Cg;
#pragma unroll
    for (int m = 0; m < 4; ++m) {
      const int row0 = bm + wm + m * 16 + lh * 4;
#pragma unroll
      for (int n = 0; n < 4; ++n) {
        const int col = bn + wn + n * 16 + lr;
        const int bb = col >> 12, sp = col & (S_ - 1);
        const float lsc = lscale[col];
#pragma unroll
        for (int r = 0; r < 4; ++r) {
          const int o = row0 + r;
          const size_t idx = ((size_t)bb * C_ + o) * S_ + sp;
          Ob[idx] = acc[m][n][r] * lsc + bias[o] + xres[idx];
        }
      }
    }
  }
}

extern "C" void kernel_launch(void* const* d_in, const int* in_sizes, int n_in,
                              void* d_out, int out_size, void* d_ws, size_t ws_size,
                              hipStream_t stream) {
  const float* x     = (const float*)d_in[0];
  const float* gamma = (const float*)d_in[1];
  const float* beta  = (const float*)d_in[2];
  const float* wq = (const float*)d_in[3];
  const float* bq = (const float*)d_in[4];
  const float* wk = (const float*)d_in[5];
  const float* bk = (const float*)d_in[6];
  const float* wv = (const float*)d_in[7];
  const float* bv = (const float*)d_in[8];
  const float* wo = (const float*)d_in[9];
  const float* bo = (const float*)d_in[10];
  float* out = (float*)d_out;

  // ws: stats 1KB | weights bf16 4x512KB | bqk 4KB | ht 16MB | qkt 32MB | vv 16MB
  //     | sc 128MB | partials 1MB | Lr 64KB | gn part 16KB
  char* ws = (char*)d_ws;
  float* stats = (float*)ws;
  u16* wqb = (u16*)(ws + 1024);
  u16* wkb = wqb + 262144;   // contiguous after wqb -> [wq;wk] is one 1024x512 matrix
  u16* wvb = wkb + 262144;
  u16* wob = wvb + 262144;
  float* bqk = (float*)(wob + 262144);
  u16* ht  = (u16*)((char*)bqk + 4096);  // [B*S, C]
  u16* qkt = ht + 8388608;               // [B*S, 1024] (q|k); later PV psum halves
  u16* vv  = qkt + 16777216;             // [C, B*S]
  u16* sc  = vv + 8388608;               // [B, S, S] exp(scores)
  float* partials = (float*)(sc + 67108864);  // [B][16][4096]
  float* Lr = partials + 262144;              // [B][4096]
  float* gnp = Lr + 16384;                    // [2048][2] gn stats partials

  // fused weight-convert + bias-concat (replaces 5 tiny dispatches)
  prep<<<4100, 256, 0, stream>>>(wq, wk, wv, wo, bq, bk, wqb, bqk);

  gn_stats_part<<<2048, 256, 0, stream>>>(x, gnp);
  gn_stats_fin<<<1, 128, 0, stream>>>(gnp, stats);
  gn_apply_t<<<dim3(64, 8, 4), 256, 0, stream>>>(x, gamma, beta, stats, ht);

  // fused Q|K projection: qkt[bs, 0:512]=Q, [512:1024]=K   (256 blocks)
  gemm8p<1, 0, 0><<<dim3(4, 64, 1), 512, 0, stream>>>(ht, 512, 0, wqb, 512, 0,
                                                      qkt, 1024, 0, bqk, 1.f, 512, nullptr);
  // V[c, b*S+s]: bias per m (=c)                            (512 blocks)
  gemm_abT<2, 0, 0><<<dim3(128, 4, 1), 256, 0, stream>>>(wvb, 512, 0, ht, 512, 0,
                                                         vv, 16384, 0, bv, 1.f,
                                                         nullptr, nullptr, nullptr, 512);
  // P[b,i,j] = exp(scale * Q.K) + row-sum partials          (1024 blocks)
  gemm8p<0, 0, 1><<<dim3(16, 16, 4), 512, 0, stream>>>(qkt, 1024, 4194304, qkt + 512, 1024, 4194304,
                                                       sc, 4096, 16777216, nullptr,
                                                       0.04419417382415922f, 512, partials);
  reduce_l<<<64, 256, 0, stream>>>(partials, Lr);
  // PV split-K=2 on unnormalized P: psums in qkt halves     (256 blocks)
  gemm8p<0, 1, 0><<<dim3(2, 16, 8), 512, 0, stream>>>(sc, 4096, 0, vv, 16384, 0,
                                                      qkt, 512, 0, nullptr, 1.f, 2048, nullptr);
  // out[b,o,s] = (Wo @ (psum0+psum1)) * Lr[bs] + bo + x      (512 blocks)
  gemm_abT<2, 1, 1><<<dim3(128, 4, 1), 256, 0, stream>>>(wob, 512, 0, qkt, 512, 0,
                                                         out, 0, 0, bo, 1.f,
                                                         x, Lr, qkt + 8388608, 512);
}